// Round 1
// baseline (7809.981 us; speedup 1.0000x reference)
//
#include <hip/hip_runtime.h>
#include <hip/hip_bf16.h>
#include <math.h>

using bf16 = __hip_bfloat16;
typedef __bf16 bf16x8 __attribute__((ext_vector_type(8)));
typedef float f32x4 __attribute__((ext_vector_type(4)));

// Problem dims
static constexpr int NB = 512;    // batch
static constexpr int NH = 1024;   // hidden
static constexpr int NOH = 4096;  // MLP inner
static constexpr int NC = 512;    // classes
static constexpr int NT = 40;     // timestamps

// ---------------------------------------------------------------------------
// Transpose-cast fp32 (K x N) -> bf16 (N x K)
// ---------------------------------------------------------------------------
__global__ void transpose_cast(const float* __restrict__ W, bf16* __restrict__ WT,
                               int K, int N) {
  __shared__ float tile[32][33];
  const int n0 = blockIdx.x * 32;
  const int k0 = blockIdx.y * 32;
  const int tx = threadIdx.x;  // 0..31
  const int ty = threadIdx.y;  // 0..7
#pragma unroll
  for (int i = 0; i < 4; ++i) {
    int r = ty + i * 8;
    tile[r][tx] = W[(size_t)(k0 + r) * N + n0 + tx];
  }
  __syncthreads();
#pragma unroll
  for (int i = 0; i < 4; ++i) {
    int r = ty + i * 8;
    WT[(size_t)(n0 + r) * K + k0 + tx] = __float2bfloat16(tile[tx][r]);
  }
}

// ---------------------------------------------------------------------------
// Init: y = z (fp32 state), yb = bf16(z), pred[0] = bf16(z)
// ---------------------------------------------------------------------------
__global__ void init_state(const float* __restrict__ z, float* __restrict__ y,
                           bf16* __restrict__ yb, bf16* __restrict__ pred0) {
  const int i = blockIdx.x * 256 + threadIdx.x;
  float v = z[i];
  y[i] = v;
  bf16 b = __float2bfloat16(v);
  yb[i] = b;
  pred0[i] = b;
}

// ---------------------------------------------------------------------------
// bf16 GEMM, B given transposed (N x K).  128x128 tile, BK=64, 4 waves (2x2),
// each wave 64x64 via 4x4 fragments of v_mfma_f32_16x16x32_bf16.
// EPI 0: out_b = bf16(tanh(acc + bias[col]))          (GEMM1, no split)
// EPI 1: out_f[kz*M*N + ...] = acc                     (GEMM2 split-K partials)
// EPI 2: out_f = acc + bias[col]                       (final logits)
// ---------------------------------------------------------------------------
template <int EPI>
__global__ void gemm_bt(const bf16* __restrict__ A, const bf16* __restrict__ BT,
                        int M, int N, int K, int kChunk,
                        const float* __restrict__ bias,
                        bf16* __restrict__ outB, float* __restrict__ outF) {
  __shared__ __align__(16) bf16 As[128 * 64];
  __shared__ __align__(16) bf16 Bs[128 * 64];

  const int tid = threadIdx.x;
  const int lane = tid & 63;
  const int wave = tid >> 6;
  const int wr = wave >> 1;
  const int wc = wave & 1;
  const int row0 = blockIdx.y * 128;
  const int col0 = blockIdx.x * 128;
  const int kz = blockIdx.z;
  const int kbeg = kz * kChunk;
  const int kend = kbeg + kChunk;

  const int l15 = lane & 15;
  const int kg = lane >> 4;

  f32x4 acc[4][4] = {};

  for (int kt = kbeg; kt < kend; kt += 64) {
    __syncthreads();
#pragma unroll
    for (int i = 0; i < 4; ++i) {
      const int c = (i << 2) | wave;            // 1KB chunk id, wave-uniform
      const int r = c * 8 + (lane >> 3);        // tile row 0..127
      const int cb = (lane & 7) * 8;            // col element offset
      const bf16* ga = A + (size_t)(row0 + r) * K + kt + cb;
      const bf16* gb = BT + (size_t)(col0 + r) * K + kt + cb;
      __builtin_amdgcn_global_load_lds(
          (const __attribute__((address_space(1))) void*)ga,
          (__attribute__((address_space(3))) void*)&As[c * 512], 16, 0, 0);
      __builtin_amdgcn_global_load_lds(
          (const __attribute__((address_space(1))) void*)gb,
          (__attribute__((address_space(3))) void*)&Bs[c * 512], 16, 0, 0);
    }
    __syncthreads();

#pragma unroll
    for (int ks = 0; ks < 64; ks += 32) {
      bf16x8 af[4], bfr[4];
      const int kb = ks + kg * 8;
#pragma unroll
      for (int mi = 0; mi < 4; ++mi)
        af[mi] = *reinterpret_cast<const bf16x8*>(&As[(wr * 64 + mi * 16 + l15) * 64 + kb]);
#pragma unroll
      for (int ni = 0; ni < 4; ++ni)
        bfr[ni] = *reinterpret_cast<const bf16x8*>(&Bs[(wc * 64 + ni * 16 + l15) * 64 + kb]);
#pragma unroll
      for (int mi = 0; mi < 4; ++mi)
#pragma unroll
        for (int ni = 0; ni < 4; ++ni)
          acc[mi][ni] = __builtin_amdgcn_mfma_f32_16x16x32_bf16(af[mi], bfr[ni],
                                                                acc[mi][ni], 0, 0, 0);
    }
  }

  // Epilogue.  C/D layout: col = lane&15, row = (lane>>4)*4 + reg
#pragma unroll
  for (int mi = 0; mi < 4; ++mi) {
    const int grow_base = row0 + wr * 64 + mi * 16 + kg * 4;
#pragma unroll
    for (int ni = 0; ni < 4; ++ni) {
      const int gcol = col0 + wc * 64 + ni * 16 + l15;
#pragma unroll
      for (int j = 0; j < 4; ++j) {
        const int grow = grow_base + j;
        const float v = acc[mi][ni][j];
        if constexpr (EPI == 0) {
          outB[(size_t)grow * N + gcol] = __float2bfloat16(tanhf(v + bias[gcol]));
        } else if constexpr (EPI == 1) {
          outF[(size_t)kz * M * N + (size_t)grow * N + gcol] = v;
        } else {
          outF[(size_t)grow * N + gcol] = v + bias[gcol];
        }
      }
    }
  }
}

// ---------------------------------------------------------------------------
// Combine split-K partials of GEMM2 and do RK4 (3/8 rule) stage algebra.
// part: 8 slices of [NB x NH].  k_s = sum(part) + b2.
// stage 1: k1 = k_s;  y_next = y + dt*k_s/3
// stage 2: k2 = k_s;  y_next = y + dt*(k_s - k1/3)
// stage 3: k3 = k_s;  y_next = y + dt*(k1 - k2 + k_s)
// stage 4: y_new = y + dt*(k1 + 3*(k2+k3) + k_s)/8 ; y = y_new; pred = bf16
// yb = bf16(y_next) always.
// ---------------------------------------------------------------------------
__global__ void combine_stage(const float* __restrict__ part,
                              const float* __restrict__ b2,
                              float* __restrict__ y, bf16* __restrict__ yb,
                              float* __restrict__ k1, float* __restrict__ k2,
                              float* __restrict__ k3, bf16* __restrict__ pred_next,
                              const float* __restrict__ ts, int t, int stage) {
  const int i = blockIdx.x * 256 + threadIdx.x;  // float4 index
  const float dt = ts[t + 1] - ts[t];
  constexpr int NE = NB * NH;

  f32x4 s = {};
#pragma unroll
  for (int z = 0; z < 8; ++z)
    s += *reinterpret_cast<const f32x4*>(part + (size_t)z * NE + (size_t)i * 4);

  const int col = (i * 4) & (NH - 1);
  const f32x4 bb = *reinterpret_cast<const f32x4*>(b2 + col);
  const f32x4 ksv = s + bb;
  const f32x4 yv = *reinterpret_cast<const f32x4*>(y + (size_t)i * 4);

  f32x4 ynext;
  if (stage == 1) {
    *reinterpret_cast<f32x4*>(k1 + (size_t)i * 4) = ksv;
    ynext = yv + ksv * (dt / 3.0f);
  } else if (stage == 2) {
    const f32x4 k1v = *reinterpret_cast<const f32x4*>(k1 + (size_t)i * 4);
    *reinterpret_cast<f32x4*>(k2 + (size_t)i * 4) = ksv;
    ynext = yv + (ksv - k1v * (1.0f / 3.0f)) * dt;
  } else if (stage == 3) {
    const f32x4 k1v = *reinterpret_cast<const f32x4*>(k1 + (size_t)i * 4);
    const f32x4 k2v = *reinterpret_cast<const f32x4*>(k2 + (size_t)i * 4);
    *reinterpret_cast<f32x4*>(k3 + (size_t)i * 4) = ksv;
    ynext = yv + (k1v - k2v + ksv) * dt;
  } else {
    const f32x4 k1v = *reinterpret_cast<const f32x4*>(k1 + (size_t)i * 4);
    const f32x4 k2v = *reinterpret_cast<const f32x4*>(k2 + (size_t)i * 4);
    const f32x4 k3v = *reinterpret_cast<const f32x4*>(k3 + (size_t)i * 4);
    ynext = yv + (k1v + (k2v + k3v) * 3.0f + ksv) * (dt * 0.125f);
    *reinterpret_cast<f32x4*>(y + (size_t)i * 4) = ynext;
    union { bf16 h[4]; unsigned long long u; } pk;
#pragma unroll
    for (int j = 0; j < 4; ++j) pk.h[j] = __float2bfloat16(ynext[j]);
    *reinterpret_cast<unsigned long long*>(pred_next + (size_t)i * 4) = pk.u;
  }

  union { bf16 h[4]; unsigned long long u; } pk2;
#pragma unroll
  for (int j = 0; j < 4; ++j) pk2.h[j] = __float2bfloat16(ynext[j]);
  *reinterpret_cast<unsigned long long*>(yb + (size_t)i * 4) = pk2.u;
}

// ---------------------------------------------------------------------------
// In-place row softmax over C=512; one wave per row.
// ---------------------------------------------------------------------------
__global__ void softmax_rows(float* __restrict__ out) {
  const int row = blockIdx.x * 4 + (threadIdx.x >> 6);
  const int lane = threadIdx.x & 63;
  float* p = out + (size_t)row * NC + lane * 8;
  f32x4 a = *reinterpret_cast<const f32x4*>(p);
  f32x4 b = *reinterpret_cast<const f32x4*>(p + 4);

  float m = fmaxf(fmaxf(fmaxf(a[0], a[1]), fmaxf(a[2], a[3])),
                  fmaxf(fmaxf(b[0], b[1]), fmaxf(b[2], b[3])));
#pragma unroll
  for (int off = 32; off > 0; off >>= 1) m = fmaxf(m, __shfl_xor(m, off));

  f32x4 ea, eb;
  float sum = 0.0f;
#pragma unroll
  for (int j = 0; j < 4; ++j) { ea[j] = expf(a[j] - m); sum += ea[j]; }
#pragma unroll
  for (int j = 0; j < 4; ++j) { eb[j] = expf(b[j] - m); sum += eb[j]; }
#pragma unroll
  for (int off = 32; off > 0; off >>= 1) sum += __shfl_xor(sum, off);

  const float inv = 1.0f / sum;
  ea *= inv;
  eb *= inv;
  *reinterpret_cast<f32x4*>(p) = ea;
  *reinterpret_cast<f32x4*>(p + 4) = eb;
}

// ---------------------------------------------------------------------------
extern "C" void kernel_launch(void* const* d_in, const int* in_sizes, int n_in,
                              void* d_out, int out_size, void* d_ws, size_t ws_size,
                              hipStream_t stream) {
  const float* z = (const float*)d_in[0];
  const float* ts = (const float*)d_in[1];
  const float* W1 = (const float*)d_in[2];
  const float* b1 = (const float*)d_in[3];
  const float* W2 = (const float*)d_in[4];
  const float* b2 = (const float*)d_in[5];
  const float* Wf = (const float*)d_in[6];
  const float* bfv = (const float*)d_in[7];

  char* w = (char*)d_ws;
  bf16* W1bT = (bf16*)w;          w += (size_t)NOH * NH * 2;        // 8 MB
  bf16* W2bT = (bf16*)w;          w += (size_t)NH * NOH * 2;        // 8 MB
  bf16* WfT  = (bf16*)w;          w += (size_t)NC * NH * 2;         // 1 MB
  float* y   = (float*)w;         w += (size_t)NB * NH * 4;         // 2 MB
  bf16* yb   = (bf16*)w;          w += (size_t)NB * NH * 2;         // 1 MB
  float* k1  = (float*)w;         w += (size_t)NB * NH * 4;
  float* k2  = (float*)w;         w += (size_t)NB * NH * 4;
  float* k3  = (float*)w;         w += (size_t)NB * NH * 4;         // 6 MB
  bf16* h    = (bf16*)w;          w += (size_t)NB * NOH * 2;        // 4 MB
  float* part = (float*)w;        w += (size_t)8 * NB * NH * 4;     // 16 MB
  bf16* pred = (bf16*)w;          w += (size_t)NT * NB * NH * 2;    // 40 MB

  float* logits = (float*)d_out;  // [NT*NB, NC] fp32, softmaxed in place

  // Weight transpose-casts (every call: kernel_launch must be stateless)
  transpose_cast<<<dim3(NOH / 32, NH / 32), dim3(32, 8), 0, stream>>>(W1, W1bT, NH, NOH);
  transpose_cast<<<dim3(NH / 32, NOH / 32), dim3(32, 8), 0, stream>>>(W2, W2bT, NOH, NH);
  transpose_cast<<<dim3(NC / 32, NH / 32), dim3(32, 8), 0, stream>>>(Wf, WfT, NH, NC);
  init_state<<<(NB * NH) / 256, 256, 0, stream>>>(z, y, yb, pred);

  for (int t = 0; t < NT - 1; ++t) {
    for (int s = 1; s <= 4; ++s) {
      // h = tanh(y_s @ W1 + b1)   [512 x 4096]
      gemm_bt<0><<<dim3(NOH / 128, NB / 128, 1), 256, 0, stream>>>(
          yb, W1bT, NB, NOH, NH, NH, b1, h, nullptr);
      // part[z] = (h @ W2) split-K partials   [8 x 512 x 1024]
      gemm_bt<1><<<dim3(NH / 128, NB / 128, 8), 256, 0, stream>>>(
          h, W2bT, NB, NH, NOH, NOH / 8, nullptr, nullptr, part);
      // k_s = sum(part) + b2 ; RK4 stage algebra -> next yb (and y/pred at s=4)
      combine_stage<<<(NB * NH / 4) / 256, 256, 0, stream>>>(
          part, b2, y, yb, k1, k2, k3, pred + (size_t)(t + 1) * NB * NH, ts, t, s);
    }
  }

  // logits = pred @ Wf + bf   [20480 x 512]
  gemm_bt<2><<<dim3(NC / 128, (NT * NB) / 128, 1), 256, 0, stream>>>(
      pred, WfT, NT * NB, NC, NH, NH, bfv, nullptr, logits);
  softmax_rows<<<(NT * NB) / 4, 256, 0, stream>>>(logits);
}

// Round 2
// 6887.627 us; speedup vs baseline: 1.1339x; 1.1339x over previous
//
#include <hip/hip_runtime.h>
#include <hip/hip_bf16.h>
#include <math.h>

using bf16 = __hip_bfloat16;
typedef __bf16 bf16x8 __attribute__((ext_vector_type(8)));
typedef float f32x4 __attribute__((ext_vector_type(4)));

// Problem dims
static constexpr int NB = 512;    // batch
static constexpr int NH = 1024;   // hidden
static constexpr int NOH = 4096;  // MLP inner
static constexpr int NC = 512;    // classes
static constexpr int NT = 40;     // timestamps
static constexpr int SPLITK = 4;  // GEMM2 split-K slices

// ---------------------------------------------------------------------------
// Transpose-cast fp32 (K x N) -> bf16 (N x K)
// ---------------------------------------------------------------------------
__global__ void transpose_cast(const float* __restrict__ W, bf16* __restrict__ WT,
                               int K, int N) {
  __shared__ float tile[32][33];
  const int n0 = blockIdx.x * 32;
  const int k0 = blockIdx.y * 32;
  const int tx = threadIdx.x;  // 0..31
  const int ty = threadIdx.y;  // 0..7
#pragma unroll
  for (int i = 0; i < 4; ++i) {
    int r = ty + i * 8;
    tile[r][tx] = W[(size_t)(k0 + r) * N + n0 + tx];
  }
  __syncthreads();
#pragma unroll
  for (int i = 0; i < 4; ++i) {
    int r = ty + i * 8;
    WT[(size_t)(n0 + r) * K + k0 + tx] = __float2bfloat16(tile[tx][r]);
  }
}

// ---------------------------------------------------------------------------
// Init: y = z (fp32 state), yb = bf16(z), pred[0] = bf16(z)
// ---------------------------------------------------------------------------
__global__ void init_state(const float* __restrict__ z, float* __restrict__ y,
                           bf16* __restrict__ yb, bf16* __restrict__ pred0) {
  const int i = blockIdx.x * 256 + threadIdx.x;
  float v = z[i];
  y[i] = v;
  bf16 b = __float2bfloat16(v);
  yb[i] = b;
  pred0[i] = b;
}

// ---------------------------------------------------------------------------
// bf16 GEMM, B given transposed (N x K).  TM x 128 tile, BK=64, 4 waves.
//   TM=128: waves 2x2, each 64x64 (acc 4x4)   — final projection
//   TM=64 : waves 1x4, each 64x32 (acc 4x2)   — GEMM1/GEMM2 (2x parallelism)
// EPI 0: out_b = bf16(tanh(acc + bias[col]))          (GEMM1)
// EPI 1: out_f[kz*M*N + ...] = acc                     (GEMM2 split-K partials)
// EPI 2: out_f = acc + bias[col]                       (final logits)
// ---------------------------------------------------------------------------
template <int TM, int EPI>
__global__ __launch_bounds__(256) void gemm_bt(
    const bf16* __restrict__ A, const bf16* __restrict__ BT,
    int M, int N, int K, int kChunk,
    const float* __restrict__ bias,
    bf16* __restrict__ outB, float* __restrict__ outF) {
  constexpr int WR = (TM == 128) ? 2 : 1;   // waves in row dim
  constexpr int WC = 4 / WR;                // waves in col dim
  constexpr int NF = 128 / WC / 16;         // col fragments per wave (4 or 2)
  constexpr int RA = TM / 32;               // A staging rounds (32 rows each)

  __shared__ __align__(16) bf16 As[TM * 64];
  __shared__ __align__(16) bf16 Bs[128 * 64];

  const int tid = threadIdx.x;
  const int lane = tid & 63;
  const int wave = tid >> 6;
  const int wr = wave / WC;
  const int wc = wave % WC;
  const int row0 = blockIdx.y * TM;
  const int col0 = blockIdx.x * 128;
  const int kz = blockIdx.z;
  const int kbeg = kz * kChunk;
  const int kend = kbeg + kChunk;

  const int l15 = lane & 15;
  const int kg = lane >> 4;

  f32x4 acc[4][NF] = {};

  const int sr = wave * 8 + (lane >> 3);   // staging row within 32-row round
  const int cb = (lane & 7) * 8;           // staging col element offset

  for (int kt = kbeg; kt < kend; kt += 64) {
    __syncthreads();
#pragma unroll
    for (int i = 0; i < RA; ++i) {
      const bf16* ga = A + (size_t)(row0 + i * 32 + sr) * K + kt + cb;
      __builtin_amdgcn_global_load_lds(
          (const __attribute__((address_space(1))) void*)ga,
          (__attribute__((address_space(3))) void*)&As[(i * 32 + wave * 8) * 64],
          16, 0, 0);
    }
#pragma unroll
    for (int i = 0; i < 4; ++i) {
      const bf16* gb = BT + (size_t)(col0 + i * 32 + sr) * K + kt + cb;
      __builtin_amdgcn_global_load_lds(
          (const __attribute__((address_space(1))) void*)gb,
          (__attribute__((address_space(3))) void*)&Bs[(i * 32 + wave * 8) * 64],
          16, 0, 0);
    }
    __syncthreads();

#pragma unroll
    for (int ks = 0; ks < 64; ks += 32) {
      bf16x8 af[4], bfr[NF];
      const int kb = ks + kg * 8;
#pragma unroll
      for (int mi = 0; mi < 4; ++mi)
        af[mi] = *reinterpret_cast<const bf16x8*>(
            &As[(wr * 64 + mi * 16 + l15) * 64 + kb]);
#pragma unroll
      for (int ni = 0; ni < NF; ++ni)
        bfr[ni] = *reinterpret_cast<const bf16x8*>(
            &Bs[(wc * (128 / WC) + ni * 16 + l15) * 64 + kb]);
#pragma unroll
      for (int mi = 0; mi < 4; ++mi)
#pragma unroll
        for (int ni = 0; ni < NF; ++ni)
          acc[mi][ni] = __builtin_amdgcn_mfma_f32_16x16x32_bf16(
              af[mi], bfr[ni], acc[mi][ni], 0, 0, 0);
    }
  }

  // Epilogue.  C/D layout: col = lane&15, row = (lane>>4)*4 + reg
#pragma unroll
  for (int mi = 0; mi < 4; ++mi) {
    const int grow_base = row0 + wr * 64 + mi * 16 + kg * 4;
#pragma unroll
    for (int ni = 0; ni < NF; ++ni) {
      const int gcol = col0 + wc * (128 / WC) + ni * 16 + l15;
#pragma unroll
      for (int j = 0; j < 4; ++j) {
        const int grow = grow_base + j;
        const float v = acc[mi][ni][j];
        if constexpr (EPI == 0) {
          outB[(size_t)grow * N + gcol] = __float2bfloat16(tanhf(v + bias[gcol]));
        } else if constexpr (EPI == 1) {
          outF[(size_t)kz * M * N + (size_t)grow * N + gcol] = v;
        } else {
          outF[(size_t)grow * N + gcol] = v + bias[gcol];
        }
      }
    }
  }
}

// ---------------------------------------------------------------------------
// Combine split-K partials of GEMM2 and do RK4 (3/8 rule) stage algebra.
// part: SPLITK slices of [NB x NH].  k_s = sum(part) + b2.
// ---------------------------------------------------------------------------
__global__ void combine_stage(const float* __restrict__ part,
                              const float* __restrict__ b2,
                              float* __restrict__ y, bf16* __restrict__ yb,
                              float* __restrict__ k1, float* __restrict__ k2,
                              float* __restrict__ k3, bf16* __restrict__ pred_next,
                              const float* __restrict__ ts, int t, int stage) {
  const int i = blockIdx.x * 256 + threadIdx.x;  // float4 index
  const float dt = ts[t + 1] - ts[t];
  constexpr int NE = NB * NH;

  f32x4 s = {};
#pragma unroll
  for (int z = 0; z < SPLITK; ++z)
    s += *reinterpret_cast<const f32x4*>(part + (size_t)z * NE + (size_t)i * 4);

  const int col = (i * 4) & (NH - 1);
  const f32x4 bb = *reinterpret_cast<const f32x4*>(b2 + col);
  const f32x4 ksv = s + bb;
  const f32x4 yv = *reinterpret_cast<const f32x4*>(y + (size_t)i * 4);

  f32x4 ynext;
  if (stage == 1) {
    *reinterpret_cast<f32x4*>(k1 + (size_t)i * 4) = ksv;
    ynext = yv + ksv * (dt / 3.0f);
  } else if (stage == 2) {
    const f32x4 k1v = *reinterpret_cast<const f32x4*>(k1 + (size_t)i * 4);
    *reinterpret_cast<f32x4*>(k2 + (size_t)i * 4) = ksv;
    ynext = yv + (ksv - k1v * (1.0f / 3.0f)) * dt;
  } else if (stage == 3) {
    const f32x4 k1v = *reinterpret_cast<const f32x4*>(k1 + (size_t)i * 4);
    const f32x4 k2v = *reinterpret_cast<const f32x4*>(k2 + (size_t)i * 4);
    *reinterpret_cast<f32x4*>(k3 + (size_t)i * 4) = ksv;
    ynext = yv + (k1v - k2v + ksv) * dt;
  } else {
    const f32x4 k1v = *reinterpret_cast<const f32x4*>(k1 + (size_t)i * 4);
    const f32x4 k2v = *reinterpret_cast<const f32x4*>(k2 + (size_t)i * 4);
    const f32x4 k3v = *reinterpret_cast<const f32x4*>(k3 + (size_t)i * 4);
    ynext = yv + (k1v + (k2v + k3v) * 3.0f + ksv) * (dt * 0.125f);
    *reinterpret_cast<f32x4*>(y + (size_t)i * 4) = ynext;
    union { bf16 h[4]; unsigned long long u; } pk;
#pragma unroll
    for (int j = 0; j < 4; ++j) pk.h[j] = __float2bfloat16(ynext[j]);
    *reinterpret_cast<unsigned long long*>(pred_next + (size_t)i * 4) = pk.u;
  }

  union { bf16 h[4]; unsigned long long u; } pk2;
#pragma unroll
  for (int j = 0; j < 4; ++j) pk2.h[j] = __float2bfloat16(ynext[j]);
  *reinterpret_cast<unsigned long long*>(yb + (size_t)i * 4) = pk2.u;
}

// ---------------------------------------------------------------------------
// In-place row softmax over C=512; one wave per row.
// ---------------------------------------------------------------------------
__global__ void softmax_rows(float* __restrict__ out) {
  const int row = blockIdx.x * 4 + (threadIdx.x >> 6);
  const int lane = threadIdx.x & 63;
  float* p = out + (size_t)row * NC + lane * 8;
  f32x4 a = *reinterpret_cast<const f32x4*>(p);
  f32x4 b = *reinterpret_cast<const f32x4*>(p + 4);

  float m = fmaxf(fmaxf(fmaxf(a[0], a[1]), fmaxf(a[2], a[3])),
                  fmaxf(fmaxf(b[0], b[1]), fmaxf(b[2], b[3])));
#pragma unroll
  for (int off = 32; off > 0; off >>= 1) m = fmaxf(m, __shfl_xor(m, off));

  f32x4 ea, eb;
  float sum = 0.0f;
#pragma unroll
  for (int j = 0; j < 4; ++j) { ea[j] = expf(a[j] - m); sum += ea[j]; }
#pragma unroll
  for (int j = 0; j < 4; ++j) { eb[j] = expf(b[j] - m); sum += eb[j]; }
#pragma unroll
  for (int off = 32; off > 0; off >>= 1) sum += __shfl_xor(sum, off);

  const float inv = 1.0f / sum;
  ea *= inv;
  eb *= inv;
  *reinterpret_cast<f32x4*>(p) = ea;
  *reinterpret_cast<f32x4*>(p + 4) = eb;
}

// ---------------------------------------------------------------------------
extern "C" void kernel_launch(void* const* d_in, const int* in_sizes, int n_in,
                              void* d_out, int out_size, void* d_ws, size_t ws_size,
                              hipStream_t stream) {
  const float* z = (const float*)d_in[0];
  const float* ts = (const float*)d_in[1];
  const float* W1 = (const float*)d_in[2];
  const float* b1 = (const float*)d_in[3];
  const float* W2 = (const float*)d_in[4];
  const float* b2 = (const float*)d_in[5];
  const float* Wf = (const float*)d_in[6];
  const float* bfv = (const float*)d_in[7];

  char* w = (char*)d_ws;
  bf16* W1bT = (bf16*)w;          w += (size_t)NOH * NH * 2;        // 8 MB
  bf16* W2bT = (bf16*)w;          w += (size_t)NH * NOH * 2;        // 8 MB
  bf16* WfT  = (bf16*)w;          w += (size_t)NC * NH * 2;         // 1 MB
  float* y   = (float*)w;         w += (size_t)NB * NH * 4;         // 2 MB
  bf16* yb   = (bf16*)w;          w += (size_t)NB * NH * 2;         // 1 MB
  float* k1  = (float*)w;         w += (size_t)NB * NH * 4;
  float* k2  = (float*)w;         w += (size_t)NB * NH * 4;
  float* k3  = (float*)w;         w += (size_t)NB * NH * 4;         // 6 MB
  bf16* h    = (bf16*)w;          w += (size_t)NB * NOH * 2;        // 4 MB
  float* part = (float*)w;        w += (size_t)SPLITK * NB * NH * 4; // 8 MB
  bf16* pred = (bf16*)w;          w += (size_t)NT * NB * NH * 2;    // 40 MB

  float* logits = (float*)d_out;  // [NT*NB, NC] fp32, softmaxed in place

  // Weight transpose-casts (every call: kernel_launch must be stateless)
  transpose_cast<<<dim3(NOH / 32, NH / 32), dim3(32, 8), 0, stream>>>(W1, W1bT, NH, NOH);
  transpose_cast<<<dim3(NH / 32, NOH / 32), dim3(32, 8), 0, stream>>>(W2, W2bT, NOH, NH);
  transpose_cast<<<dim3(NC / 32, NH / 32), dim3(32, 8), 0, stream>>>(Wf, WfT, NH, NC);
  init_state<<<(NB * NH) / 256, 256, 0, stream>>>(z, y, yb, pred);

  for (int t = 0; t < NT - 1; ++t) {
    for (int s = 1; s <= 4; ++s) {
      // h = tanh(y_s @ W1 + b1)   [512 x 4096], 64-row tiles -> 256 WGs
      gemm_bt<64, 0><<<dim3(NOH / 128, NB / 64, 1), 256, 0, stream>>>(
          yb, W1bT, NB, NOH, NH, NH, b1, h, nullptr);
      // part[z] = (h @ W2) split-K partials   [SPLITK x 512 x 1024] -> 256 WGs
      gemm_bt<64, 1><<<dim3(NH / 128, NB / 64, SPLITK), 256, 0, stream>>>(
          h, W2bT, NB, NH, NOH, NOH / SPLITK, nullptr, nullptr, part);
      // k_s = sum(part) + b2 ; RK4 stage algebra -> next yb (and y/pred at s=4)
      combine_stage<<<(NB * NH / 4) / 256, 256, 0, stream>>>(
          part, b2, y, yb, k1, k2, k3, pred + (size_t)(t + 1) * NB * NH, ts, t, s);
    }
  }

  // logits = pred @ Wf + bf   [20480 x 512]
  gemm_bt<128, 2><<<dim3(NC / 128, (NT * NB) / 128, 1), 256, 0, stream>>>(
      pred, WfT, NT * NB, NC, NH, NH, bfv, nullptr, logits);
  softmax_rows<<<(NT * NB) / 4, 256, 0, stream>>>(logits);
}

// Round 3
// 5924.426 us; speedup vs baseline: 1.3183x; 1.1626x over previous
//
#include <hip/hip_runtime.h>
#include <hip/hip_bf16.h>
#include <math.h>

using bf16 = __hip_bfloat16;
typedef __bf16 bf16x8 __attribute__((ext_vector_type(8)));
typedef float f32x4 __attribute__((ext_vector_type(4)));

// Problem dims
static constexpr int NB = 512;    // batch
static constexpr int NH = 1024;   // hidden
static constexpr int NOH = 4096;  // MLP inner
static constexpr int NC = 512;    // classes
static constexpr int NT = 40;     // timestamps
static constexpr int SPLITK = 4;  // GEMM2 split-K slices

// ---------------------------------------------------------------------------
// Transpose-cast fp32 (K x N) -> bf16 (N x K)
// ---------------------------------------------------------------------------
__global__ void transpose_cast(const float* __restrict__ W, bf16* __restrict__ WT,
                               int K, int N) {
  __shared__ float tile[32][33];
  const int n0 = blockIdx.x * 32;
  const int k0 = blockIdx.y * 32;
  const int tx = threadIdx.x;  // 0..31
  const int ty = threadIdx.y;  // 0..7
#pragma unroll
  for (int i = 0; i < 4; ++i) {
    int r = ty + i * 8;
    tile[r][tx] = W[(size_t)(k0 + r) * N + n0 + tx];
  }
  __syncthreads();
#pragma unroll
  for (int i = 0; i < 4; ++i) {
    int r = ty + i * 8;
    WT[(size_t)(n0 + r) * K + k0 + tx] = __float2bfloat16(tile[tx][r]);
  }
}

// ---------------------------------------------------------------------------
// Init: y = z (fp32 state), yb = bf16(z), pred[0] = bf16(z)
// ---------------------------------------------------------------------------
__global__ void init_state(const float* __restrict__ z, float* __restrict__ y,
                           bf16* __restrict__ yb, bf16* __restrict__ pred0) {
  const int i = blockIdx.x * 256 + threadIdx.x;
  float v = z[i];
  y[i] = v;
  bf16 b = __float2bfloat16(v);
  yb[i] = b;
  pred0[i] = b;
}

// ---------------------------------------------------------------------------
// bf16 GEMM, B given transposed (N x K).  TM x TN tile, BK=64, 4 waves (2x2),
// double-buffered LDS with prefetch-ahead (minimum 2-phase pipeline):
//   prologue: STAGE(buf0); barrier
//   iter:     STAGE(buf^1, next) ; ds_read+MFMA(buf) ; barrier ; swap
// One barrier (vmcnt(0)+lgkmcnt(0) drain) per K-iter; prefetch latency hides
// under the current tile's compute.
// EPI 0: out_b = bf16(tanh(acc + bias[col]))          (GEMM1)
// EPI 1: out_f[kz*M*N + ...] = acc                     (GEMM2 split-K partials)
// EPI 2: out_f = acc + bias[col]                       (final logits)
// ---------------------------------------------------------------------------
template <int TM, int TN, int EPI>
__global__ __launch_bounds__(256) void gemm_bt(
    const bf16* __restrict__ A, const bf16* __restrict__ BT,
    int M, int N, int K, int kChunk,
    const float* __restrict__ bias,
    bf16* __restrict__ outB, float* __restrict__ outF) {
  constexpr int MF = TM / 32;  // row fragments per wave (waves 2x2)
  constexpr int NF = TN / 32;  // col fragments per wave
  constexpr int RA = TM / 32;  // A staging rounds (32 rows / round)
  constexpr int RB = TN / 32;  // B staging rounds

  __shared__ __align__(16) bf16 As[2][TM * 64];
  __shared__ __align__(16) bf16 Bs[2][TN * 64];

  const int tid = threadIdx.x;
  const int lane = tid & 63;
  const int wave = tid >> 6;
  const int wr = wave >> 1;
  const int wc = wave & 1;
  const int row0 = blockIdx.y * TM;
  const int col0 = blockIdx.x * TN;
  const int kz = blockIdx.z;
  const int kbeg = kz * kChunk;
  const int kend = kbeg + kChunk;

  const int l15 = lane & 15;
  const int kg = lane >> 4;

  const int sr = wave * 8 + (lane >> 3);  // row within 32-row staging round
  const int cb = (lane & 7) * 8;          // col element offset

  f32x4 acc[MF][NF] = {};

  auto stage = [&](int buf, int kt) {
#pragma unroll
    for (int i = 0; i < RA; ++i) {
      const bf16* ga = A + (size_t)(row0 + i * 32 + sr) * K + kt + cb;
      __builtin_amdgcn_global_load_lds(
          (const __attribute__((address_space(1))) void*)ga,
          (__attribute__((address_space(3))) void*)&As[buf][(i * 32 + wave * 8) * 64],
          16, 0, 0);
    }
#pragma unroll
    for (int i = 0; i < RB; ++i) {
      const bf16* gb = BT + (size_t)(col0 + i * 32 + sr) * K + kt + cb;
      __builtin_amdgcn_global_load_lds(
          (const __attribute__((address_space(1))) void*)gb,
          (__attribute__((address_space(3))) void*)&Bs[buf][(i * 32 + wave * 8) * 64],
          16, 0, 0);
    }
  };

  stage(0, kbeg);
  __syncthreads();
  int cur = 0;

  for (int kt = kbeg; kt < kend; kt += 64) {
    if (kt + 64 < kend) stage(cur ^ 1, kt + 64);  // prefetch next tile

#pragma unroll
    for (int ks = 0; ks < 64; ks += 32) {
      bf16x8 af[MF], bfr[NF];
      const int kb = ks + kg * 8;
#pragma unroll
      for (int mi = 0; mi < MF; ++mi)
        af[mi] = *reinterpret_cast<const bf16x8*>(
            &As[cur][(wr * (TM / 2) + mi * 16 + l15) * 64 + kb]);
#pragma unroll
      for (int ni = 0; ni < NF; ++ni)
        bfr[ni] = *reinterpret_cast<const bf16x8*>(
            &Bs[cur][(wc * (TN / 2) + ni * 16 + l15) * 64 + kb]);
#pragma unroll
      for (int mi = 0; mi < MF; ++mi)
#pragma unroll
        for (int ni = 0; ni < NF; ++ni)
          acc[mi][ni] = __builtin_amdgcn_mfma_f32_16x16x32_bf16(
              af[mi], bfr[ni], acc[mi][ni], 0, 0, 0);
    }
    __syncthreads();  // vmcnt(0)+lgkmcnt(0) drain: prefetched tile now ready
    cur ^= 1;
  }

  // Epilogue.  C/D layout: col = lane&15, row = (lane>>4)*4 + reg
#pragma unroll
  for (int mi = 0; mi < MF; ++mi) {
    const int grow_base = row0 + wr * (TM / 2) + mi * 16 + kg * 4;
#pragma unroll
    for (int ni = 0; ni < NF; ++ni) {
      const int gcol = col0 + wc * (TN / 2) + ni * 16 + l15;
#pragma unroll
      for (int j = 0; j < 4; ++j) {
        const int grow = grow_base + j;
        const float v = acc[mi][ni][j];
        if constexpr (EPI == 0) {
          outB[(size_t)grow * N + gcol] = __float2bfloat16(tanhf(v + bias[gcol]));
        } else if constexpr (EPI == 1) {
          outF[(size_t)kz * M * N + (size_t)grow * N + gcol] = v;
        } else {
          outF[(size_t)grow * N + gcol] = v + bias[gcol];
        }
      }
    }
  }
}

// ---------------------------------------------------------------------------
// Combine split-K partials of GEMM2 and do RK4 (3/8 rule) stage algebra.
// part: SPLITK slices of [NB x NH].  k_s = sum(part) + b2.
// ---------------------------------------------------------------------------
__global__ void combine_stage(const float* __restrict__ part,
                              const float* __restrict__ b2,
                              float* __restrict__ y, bf16* __restrict__ yb,
                              float* __restrict__ k1, float* __restrict__ k2,
                              float* __restrict__ k3, bf16* __restrict__ pred_next,
                              const float* __restrict__ ts, int t, int stage) {
  const int i = blockIdx.x * 256 + threadIdx.x;  // float4 index
  const float dt = ts[t + 1] - ts[t];
  constexpr int NE = NB * NH;

  f32x4 s = {};
#pragma unroll
  for (int z = 0; z < SPLITK; ++z)
    s += *reinterpret_cast<const f32x4*>(part + (size_t)z * NE + (size_t)i * 4);

  const int col = (i * 4) & (NH - 1);
  const f32x4 bb = *reinterpret_cast<const f32x4*>(b2 + col);
  const f32x4 ksv = s + bb;
  const f32x4 yv = *reinterpret_cast<const f32x4*>(y + (size_t)i * 4);

  f32x4 ynext;
  if (stage == 1) {
    *reinterpret_cast<f32x4*>(k1 + (size_t)i * 4) = ksv;
    ynext = yv + ksv * (dt / 3.0f);
  } else if (stage == 2) {
    const f32x4 k1v = *reinterpret_cast<const f32x4*>(k1 + (size_t)i * 4);
    *reinterpret_cast<f32x4*>(k2 + (size_t)i * 4) = ksv;
    ynext = yv + (ksv - k1v * (1.0f / 3.0f)) * dt;
  } else if (stage == 3) {
    const f32x4 k1v = *reinterpret_cast<const f32x4*>(k1 + (size_t)i * 4);
    const f32x4 k2v = *reinterpret_cast<const f32x4*>(k2 + (size_t)i * 4);
    *reinterpret_cast<f32x4*>(k3 + (size_t)i * 4) = ksv;
    ynext = yv + (k1v - k2v + ksv) * dt;
  } else {
    const f32x4 k1v = *reinterpret_cast<const f32x4*>(k1 + (size_t)i * 4);
    const f32x4 k2v = *reinterpret_cast<const f32x4*>(k2 + (size_t)i * 4);
    const f32x4 k3v = *reinterpret_cast<const f32x4*>(k3 + (size_t)i * 4);
    ynext = yv + (k1v + (k2v + k3v) * 3.0f + ksv) * (dt * 0.125f);
    *reinterpret_cast<f32x4*>(y + (size_t)i * 4) = ynext;
    union { bf16 h[4]; unsigned long long u; } pk;
#pragma unroll
    for (int j = 0; j < 4; ++j) pk.h[j] = __float2bfloat16(ynext[j]);
    *reinterpret_cast<unsigned long long*>(pred_next + (size_t)i * 4) = pk.u;
  }

  union { bf16 h[4]; unsigned long long u; } pk2;
#pragma unroll
  for (int j = 0; j < 4; ++j) pk2.h[j] = __float2bfloat16(ynext[j]);
  *reinterpret_cast<unsigned long long*>(yb + (size_t)i * 4) = pk2.u;
}

// ---------------------------------------------------------------------------
// In-place row softmax over C=512; one wave per row.
// ---------------------------------------------------------------------------
__global__ void softmax_rows(float* __restrict__ out) {
  const int row = blockIdx.x * 4 + (threadIdx.x >> 6);
  const int lane = threadIdx.x & 63;
  float* p = out + (size_t)row * NC + lane * 8;
  f32x4 a = *reinterpret_cast<const f32x4*>(p);
  f32x4 b = *reinterpret_cast<const f32x4*>(p + 4);

  float m = fmaxf(fmaxf(fmaxf(a[0], a[1]), fmaxf(a[2], a[3])),
                  fmaxf(fmaxf(b[0], b[1]), fmaxf(b[2], b[3])));
#pragma unroll
  for (int off = 32; off > 0; off >>= 1) m = fmaxf(m, __shfl_xor(m, off));

  f32x4 ea, eb;
  float sum = 0.0f;
#pragma unroll
  for (int j = 0; j < 4; ++j) { ea[j] = expf(a[j] - m); sum += ea[j]; }
#pragma unroll
  for (int j = 0; j < 4; ++j) { eb[j] = expf(b[j] - m); sum += eb[j]; }
#pragma unroll
  for (int off = 32; off > 0; off >>= 1) sum += __shfl_xor(sum, off);

  const float inv = 1.0f / sum;
  ea *= inv;
  eb *= inv;
  *reinterpret_cast<f32x4*>(p) = ea;
  *reinterpret_cast<f32x4*>(p + 4) = eb;
}

// ---------------------------------------------------------------------------
extern "C" void kernel_launch(void* const* d_in, const int* in_sizes, int n_in,
                              void* d_out, int out_size, void* d_ws, size_t ws_size,
                              hipStream_t stream) {
  const float* z = (const float*)d_in[0];
  const float* ts = (const float*)d_in[1];
  const float* W1 = (const float*)d_in[2];
  const float* b1 = (const float*)d_in[3];
  const float* W2 = (const float*)d_in[4];
  const float* b2 = (const float*)d_in[5];
  const float* Wf = (const float*)d_in[6];
  const float* bfv = (const float*)d_in[7];

  char* w = (char*)d_ws;
  bf16* W1bT = (bf16*)w;          w += (size_t)NOH * NH * 2;        // 8 MB
  bf16* W2bT = (bf16*)w;          w += (size_t)NH * NOH * 2;        // 8 MB
  bf16* WfT  = (bf16*)w;          w += (size_t)NC * NH * 2;         // 1 MB
  float* y   = (float*)w;         w += (size_t)NB * NH * 4;         // 2 MB
  bf16* yb   = (bf16*)w;          w += (size_t)NB * NH * 2;         // 1 MB
  float* k1  = (float*)w;         w += (size_t)NB * NH * 4;
  float* k2  = (float*)w;         w += (size_t)NB * NH * 4;
  float* k3  = (float*)w;         w += (size_t)NB * NH * 4;         // 6 MB
  bf16* h    = (bf16*)w;          w += (size_t)NB * NOH * 2;        // 4 MB
  float* part = (float*)w;        w += (size_t)SPLITK * NB * NH * 4; // 8 MB
  bf16* pred = (bf16*)w;          w += (size_t)NT * NB * NH * 2;    // 40 MB

  float* logits = (float*)d_out;  // [NT*NB, NC] fp32, softmaxed in place

  // Weight transpose-casts (every call: kernel_launch must be stateless)
  transpose_cast<<<dim3(NOH / 32, NH / 32), dim3(32, 8), 0, stream>>>(W1, W1bT, NH, NOH);
  transpose_cast<<<dim3(NH / 32, NOH / 32), dim3(32, 8), 0, stream>>>(W2, W2bT, NOH, NH);
  transpose_cast<<<dim3(NC / 32, NH / 32), dim3(32, 8), 0, stream>>>(Wf, WfT, NH, NC);
  init_state<<<(NB * NH) / 256, 256, 0, stream>>>(z, y, yb, pred);

  for (int t = 0; t < NT - 1; ++t) {
    for (int s = 1; s <= 4; ++s) {
      // h = tanh(y_s @ W1 + b1)   [512 x 4096], 64x64 tiles -> 512 WGs (2/CU)
      gemm_bt<64, 64, 0><<<dim3(NOH / 64, NB / 64, 1), 256, 0, stream>>>(
          yb, W1bT, NB, NOH, NH, NH, b1, h, nullptr);
      // part[z] = (h @ W2) split-K partials  [SPLITK x 512 x 1024] -> 512 WGs
      gemm_bt<64, 64, 1><<<dim3(NH / 64, NB / 64, SPLITK), 256, 0, stream>>>(
          h, W2bT, NB, NH, NOH, NOH / SPLITK, nullptr, nullptr, part);
      // k_s = sum(part) + b2 ; RK4 stage algebra -> next yb (and y/pred at s=4)
      combine_stage<<<(NB * NH / 4) / 256, 256, 0, stream>>>(
          part, b2, y, yb, k1, k2, k3, pred + (size_t)(t + 1) * NB * NH, ts, t, s);
    }
  }

  // logits = pred @ Wf + bf   [20480 x 512]
  gemm_bt<128, 128, 2><<<dim3(NC / 128, (NT * NB) / 128, 1), 256, 0, stream>>>(
      pred, WfT, NT * NB, NC, NH, NH, bfv, nullptr, logits);
  softmax_rows<<<(NT * NB) / 4, 256, 0, stream>>>(logits);
}